// Round 1
// baseline (3845.415 us; speedup 1.0000x reference)
//
#include <hip/hip_runtime.h>
#include <math.h>

#define N_NODES 100000
#define N_EDGES 400000
#define POSD 3
#define F 128
#define M 16
#define FE 16
#define EIN 289     // 2F + 2FE + 1
#define EHID 578
#define NIN 144
#define NHID 256
#define ROW 131
#define LNEPS 1e-5f

#define EPB 8   // edges per block
#define NPB 8   // nodes per block

__device__ __forceinline__ float silu_f(float v) {
    return v / (1.f + __expf(-v));
}

// ---------------- Edge kernel: build input, MLP1, MLP2, LN, scatter-add ----
__global__ __launch_bounds__(256) void edge_kernel(
    const float* __restrict__ x, const int* __restrict__ ei,
    const float* __restrict__ w1, const float* __restrict__ b1,
    const float* __restrict__ w2, const float* __restrict__ b2,
    const float* __restrict__ g1, const float* __restrict__ bb1,
    float* __restrict__ m_i)
{
    __shared__ float in_s[EPB][EIN];    // 9.2 KB
    __shared__ float hid_s[EPB][EHID];  // 18.5 KB
    __shared__ float d_s[EPB];
    __shared__ int   src_s[EPB], dst_s[EPB];

    const int t = threadIdx.x;
    const long long ebase = (long long)blockIdx.x * EPB;  // E % EPB == 0

    if (t < EPB) {
        long long e = ebase + t;
        int s = ei[e];
        int d = ei[(long long)N_EDGES + e];
        src_s[t] = s; dst_s[t] = d;
        float dx = x[(long long)s*ROW+0] - x[(long long)d*ROW+0];
        float dy = x[(long long)s*ROW+1] - x[(long long)d*ROW+1];
        float dz = x[(long long)s*ROW+2] - x[(long long)d*ROW+2];
        d_s[t] = dx*dx + dy*dy + dz*dz;
    }
    __syncthreads();

    // stage inputs: [feats[dst] | feats[src] | sin(ds) | cos(ds) | d]
    for (int idx = t; idx < EPB*EIN; idx += 256) {
        int e = idx / EIN;
        int k = idx - e*EIN;
        float v;
        if (k < F) {
            v = x[(long long)dst_s[e]*ROW + POSD + k];
        } else if (k < 2*F) {
            v = x[(long long)src_s[e]*ROW + POSD + (k - F)];
        } else if (k < 2*F + FE) {
            v = sinf(ldexpf(d_s[e], -(k - 2*F)));
        } else if (k < 2*F + 2*FE) {
            v = cosf(ldexpf(d_s[e], -(k - 2*F - FE)));
        } else {
            v = d_s[e];
        }
        in_s[e][k] = v;
    }
    __syncthreads();

    // MLP1: 289 -> 578, each thread owns cols {t, t+256, t+512(if t<66)} x 8 edges
    float acc0[EPB], acc1[EPB], acc2[EPB];
    #pragma unroll
    for (int e = 0; e < EPB; ++e) { acc0[e]=0.f; acc1[e]=0.f; acc2[e]=0.f; }
    const bool has3 = (t < EHID - 512);
    for (int k = 0; k < EIN; ++k) {
        const float* wrow = w1 + (long long)k * EHID;
        float wa = wrow[t];
        float wb = wrow[t + 256];
        float wc = has3 ? wrow[t + 512] : 0.f;
        #pragma unroll
        for (int e = 0; e < EPB; ++e) {
            float iv = in_s[e][k];
            acc0[e] = fmaf(iv, wa, acc0[e]);
            acc1[e] = fmaf(iv, wb, acc1[e]);
            acc2[e] = fmaf(iv, wc, acc2[e]);
        }
    }
    {
        float ba = b1[t], bb = b1[t+256], bc = has3 ? b1[t+512] : 0.f;
        #pragma unroll
        for (int e = 0; e < EPB; ++e) {
            hid_s[e][t]       = silu_f(acc0[e] + ba);
            hid_s[e][t + 256] = silu_f(acc1[e] + bb);
            if (has3) hid_s[e][t + 512] = silu_f(acc2[e] + bc);
        }
    }
    __syncthreads();

    // MLP2: 578 -> 16, silu, LN(16), atomic scatter to m_i[dst]
    if (t < EPB * M) {
        int e  = t >> 4;
        int oc = t & 15;
        float acc = 0.f;
        for (int k = 0; k < EHID; ++k)
            acc = fmaf(hid_s[e][k], w2[k*M + oc], acc);
        acc = silu_f(acc + b2[oc]);
        float s = acc, s2 = acc*acc;
        #pragma unroll
        for (int m = 8; m >= 1; m >>= 1) {
            s  += __shfl_xor(s,  m, 16);
            s2 += __shfl_xor(s2, m, 16);
        }
        float mean = s * (1.f/16.f);
        float var  = s2 * (1.f/16.f) - mean*mean;
        float rs   = rsqrtf(var + LNEPS);
        float v    = (acc - mean) * rs * g1[oc] + bb1[oc];
        atomicAdd(&m_i[(long long)dst_s[e]*M + oc], v);
    }
}

// ---------------- Node kernel: LN(m_i), LN(feats), MLP, LN, residual -------
__global__ __launch_bounds__(256) void node_kernel(
    const float* __restrict__ x, const float* __restrict__ m_i,
    const float* __restrict__ en2g, const float* __restrict__ en2b,
    const float* __restrict__ nn1g, const float* __restrict__ nn1b,
    const float* __restrict__ w1, const float* __restrict__ b1,
    const float* __restrict__ w2, const float* __restrict__ b2,
    const float* __restrict__ nn2g, const float* __restrict__ nn2b,
    float* __restrict__ out)
{
    __shared__ float hin[NPB][NIN];    // 4.6 KB
    __shared__ float hid[NPB][NHID];   // 8 KB
    __shared__ float rsum[4], rsq[4];

    const int t = threadIdx.x;
    const long long nb = (long long)blockIdx.x * NPB;  // N % NPB == 0
    const int g = t >> 5, l = t & 31;                  // 8 node-groups of 32
    const long long node = nb + g;

    // LN(feats) -> hin[g][0..127]
    {
        const float* xr = x + node*ROW + POSD;
        float vals[4]; float s = 0.f, s2 = 0.f;
        #pragma unroll
        for (int i = 0; i < 4; ++i) {
            float v = xr[l*4 + i];
            vals[i] = v; s += v; s2 += v*v;
        }
        #pragma unroll
        for (int m = 16; m >= 1; m >>= 1) {
            s  += __shfl_xor(s,  m, 32);
            s2 += __shfl_xor(s2, m, 32);
        }
        float mean = s * (1.f/128.f);
        float var  = s2 * (1.f/128.f) - mean*mean;
        float rs   = rsqrtf(var + LNEPS);
        #pragma unroll
        for (int i = 0; i < 4; ++i) {
            int c = l*4 + i;
            hin[g][c] = (vals[i] - mean) * rs * nn1g[c] + nn1b[c];
        }
    }
    // LN(m_i) -> hin[g][128..143]
    if (l < 16) {
        float v = m_i[node*M + l];
        float a = v, a2 = v*v;
        #pragma unroll
        for (int m = 8; m >= 1; m >>= 1) {
            a  += __shfl_xor(a,  m, 16);
            a2 += __shfl_xor(a2, m, 16);
        }
        float mn = a * (1.f/16.f);
        float vr = a2 * (1.f/16.f) - mn*mn;
        float r2 = rsqrtf(vr + LNEPS);
        hin[g][F + l] = (v - mn) * r2 * en2g[l] + en2b[l];
    }
    __syncthreads();

    // hidden: 144 -> 256, thread t owns col t for all 8 nodes
    {
        float acc[NPB];
        #pragma unroll
        for (int e = 0; e < NPB; ++e) acc[e] = 0.f;
        for (int k = 0; k < NIN; ++k) {
            float w = w1[k*NHID + t];
            #pragma unroll
            for (int e = 0; e < NPB; ++e)
                acc[e] = fmaf(hin[e][k], w, acc[e]);
        }
        float b = b1[t];
        #pragma unroll
        for (int e = 0; e < NPB; ++e)
            hid[e][t] = silu_f(acc[e] + b);
    }
    __syncthreads();

    // out layer: 256 -> 128, LN(128), residual; 2 nodes per pass, 4 passes
    const int col = t & 127;
    const int sub = t >> 7;   // 0 or 1: which node of the pass
    const int wv  = t >> 6;   // wave id 0..3
    for (int p = 0; p < 4; ++p) {
        int e = p*2 + sub;
        float y = b2[col];
        for (int k = 0; k < NHID; ++k)
            y = fmaf(hid[e][k], w2[k*F + col], y);
        float a = y, a2 = y*y;
        #pragma unroll
        for (int m = 32; m >= 1; m >>= 1) {
            a  += __shfl_xor(a,  m, 64);
            a2 += __shfl_xor(a2, m, 64);
        }
        if ((t & 63) == 0) { rsum[wv] = a; rsq[wv] = a2; }
        __syncthreads();
        float ts  = rsum[sub*2] + rsum[sub*2 + 1];
        float ts2 = rsq[sub*2]  + rsq[sub*2 + 1];
        float mn  = ts * (1.f/128.f);
        float vr  = ts2 * (1.f/128.f) - mn*mn;
        float r   = rsqrtf(vr + LNEPS);
        long long no = nb + e;
        float res = x[no*ROW + POSD + col];
        out[no*ROW + POSD + col] = res + (y - mn) * r * nn2g[col] + nn2b[col];
        if (col < POSD)
            out[no*ROW + col] = x[no*ROW + col];
        __syncthreads();
    }
}

extern "C" void kernel_launch(void* const* d_in, const int* in_sizes, int n_in,
                              void* d_out, int out_size, void* d_ws, size_t ws_size,
                              hipStream_t stream) {
    const float* x    = (const float*)d_in[0];
    const int*   ei   = (const int*)d_in[1];
    const float* e_w1 = (const float*)d_in[2];
    const float* e_b1 = (const float*)d_in[3];
    const float* e_w2 = (const float*)d_in[4];
    const float* e_b2 = (const float*)d_in[5];
    const float* en1g = (const float*)d_in[6];
    const float* en1b = (const float*)d_in[7];
    const float* en2g = (const float*)d_in[8];
    const float* en2b = (const float*)d_in[9];
    const float* nn1g = (const float*)d_in[10];
    const float* nn1b = (const float*)d_in[11];
    const float* n_w1 = (const float*)d_in[12];
    const float* n_b1 = (const float*)d_in[13];
    const float* n_w2 = (const float*)d_in[14];
    const float* n_b2 = (const float*)d_in[15];
    const float* nn2g = (const float*)d_in[16];
    const float* nn2b = (const float*)d_in[17];
    float* out = (float*)d_out;
    float* m_i = (float*)d_ws;   // N_NODES * M floats = 6.4 MB

    hipMemsetAsync(m_i, 0, (size_t)N_NODES * M * sizeof(float), stream);
    edge_kernel<<<N_EDGES / EPB, 256, 0, stream>>>(
        x, ei, e_w1, e_b1, e_w2, e_b2, en1g, en1b, m_i);
    node_kernel<<<N_NODES / NPB, 256, 0, stream>>>(
        x, m_i, en2g, en2b, nn1g, nn1b, n_w1, n_b1, n_w2, n_b2, nn2g, nn2b, out);
}

// Round 4
// 1179.478 us; speedup vs baseline: 3.2603x; 3.2603x over previous
//
#include <hip/hip_runtime.h>
#include <math.h>

#define N_NODES 100000
#define N_EDGES 400000
#define POSD 3
#define F 128
#define M 16
#define EIN 289
#define EHID 578
#define NIN 144
#define NHID 256
#define ROW 131
#define LNEPS 1e-5f

// GEMM1 (edge MLP1) padded dims
#define KP 320      // K: 289 -> 320, 10 slices of 32 (40 groups of 8: bijective XOR)
#define NP 640      // N: 578 -> 640, 40 tiles of 16
#define EPB 32      // edges per block
#define NSLICE 10
#define HIDP 640    // GEMM2 K padding: 80 groups of 8 -> XOR swizzle bijective per row
                    // (608 was NON-bijective: groups 72..75 spilled into next row = the bug)

#define NPB 8       // nodes per block (node kernel)

typedef _Float16 half8 __attribute__((ext_vector_type(8)));
typedef float f32x4 __attribute__((ext_vector_type(4)));

__device__ __forceinline__ float silu_f(float v) { return v / (1.f + __expf(-v)); }

__device__ __forceinline__ void gload_lds16(const void* g, void* l) {
    __builtin_amdgcn_global_load_lds(
        (const __attribute__((address_space(1))) unsigned int*)g,
        (__attribute__((address_space(3))) unsigned int*)l, 16, 0, 0);
}

// ---------------- weight prep: w1 -> fp16 k-sliced swizzled, w2 -> fp16 T ---
// w1ks element (slice s, col c, kk in 0..31) stored at
//   s*NP*32 + c*32 + (((kk>>3) ^ ((c>>1)&3))<<3) + (kk&7)
// so a LINEAR global_load_lds stage produces the swizzled LDS layout the
// b-frag ds_read_b128 expects (both-sides-or-neither, rule 21).
__global__ __launch_bounds__(256) void prep_weights(
    const float* __restrict__ w1, const float* __restrict__ w2,
    _Float16* __restrict__ w1ks, _Float16* __restrict__ w2t)
{
    long long idx = (long long)blockIdx.x * 256 + threadIdx.x;
    const long long n1 = (long long)NSLICE * NP * 32;  // 204800
    if (idx < n1) {
        int s   = (int)(idx / (NP * 32));
        int rem = (int)(idx - (long long)s * (NP * 32));
        int c   = rem >> 5;
        int kk  = rem & 31;
        int k   = s * 32 + kk;
        float v = (k < EIN && c < EHID) ? w1[(long long)k * EHID + c] : 0.f;
        int off = (((kk >> 3) ^ ((c >> 1) & 3)) << 3) + (kk & 7);
        w1ks[(long long)s * (NP * 32) + c * 32 + off] = (_Float16)v;
    } else {
        long long j = idx - n1;
        if (j < (long long)M * HIDP) {
            int oc = (int)(j / HIDP);
            int k  = (int)(j - (long long)oc * HIDP);
            float v = (k < EHID) ? w2[(long long)k * M + oc] : 0.f;
            w2t[j] = (_Float16)v;
        }
    }
}

// ---------------- Edge kernel: MFMA GEMM1 + GEMM2, LN, scatter-add ---------
// All MFMAs are the verified 16x16x32 shape:
//   A row = lane&15, k-group = lane>>4; B col = lane&15, k-group = lane>>4;
//   C/D: col = lane&15, row = (lane>>4)*4 + reg.
__global__ __launch_bounds__(256, 2) void edge_kernel(
    const float* __restrict__ x, const int* __restrict__ ei,
    const _Float16* __restrict__ w1ks, const float* __restrict__ b1,
    const _Float16* __restrict__ w2t, const float* __restrict__ b2,
    const float* __restrict__ g1, const float* __restrict__ bb1,
    float* __restrict__ m_i)
{
    __shared__ __align__(16) _Float16 lds_A[EPB * KP];  // 20480 B, swizzled [32][320]
    __shared__ __align__(16) _Float16 lds_B[NP * 32];   // 40960 B; later hid[32][640]
    __shared__ int   src_s[EPB], dst_s[EPB];
    __shared__ float d_s[EPB];

    const int t    = threadIdx.x;
    const int lane = t & 63;
    const int wv   = t >> 6;
    const int cl16 = lane & 15;
    const int h4   = lane >> 4;
    const long long ebase = (long long)blockIdx.x * EPB;

    if (t < EPB) {
        int s = ei[ebase + t];
        int d = ei[(long long)N_EDGES + ebase + t];
        src_s[t] = s; dst_s[t] = d;
        float dx = x[(long long)s*ROW+0] - x[(long long)d*ROW+0];
        float dy = x[(long long)s*ROW+1] - x[(long long)d*ROW+1];
        float dz = x[(long long)s*ROW+2] - x[(long long)d*ROW+2];
        d_s[t] = dx*dx + dy*dy + dz*dz;
    }
    __syncthreads();

    // ---- A staging (fp16, XOR-swizzled): element k of row r goes to
    //      r*KP + (((k>>3) ^ (r&7))<<3) + (k&7)   (40 groups: bijective)
    for (int i = t; i < EPB * 256; i += 256) {
        int row = i >> 8, k = i & 255;
        int node = (k < F) ? dst_s[row] : src_s[row];
        float v = x[(long long)node * ROW + POSD + (k & 127)];
        lds_A[row * KP + (((k >> 3) ^ (row & 7)) << 3) + (k & 7)] = (_Float16)v;
    }
    for (int i = t; i < EPB * 64; i += 256) {
        int row = i >> 6, j = i & 63;
        int k = 256 + j;
        float v;
        if (j < 16)       v = sinf(ldexpf(d_s[row], -j));
        else if (j < 32)  v = cosf(ldexpf(d_s[row], -(j - 16)));
        else if (j == 32) v = d_s[row];
        else              v = 0.f;
        lds_A[row * KP + (((k >> 3) ^ (row & 7)) << 3) + (k & 7)] = (_Float16)v;
    }

    // ---- GEMM1: [32 x 320] @ [320 x 640], 16x16x32 fp16 MFMA
    // wave wv owns N-tiles wv*10 .. wv*10+9 for both M-tiles.
    f32x4 acc[2][10] = {};
    const int bxor = (cl16 >> 1) & 3;

    for (int s = 0; s < NSLICE; ++s) {
        __syncthreads();  // prior slice's B reads done (s=0: A staging done)
        {
            const _Float16* gsrc = w1ks + (long long)s * (NP * 32);
            #pragma unroll
            for (int i = 0; i < 10; ++i)
                gload_lds16((const char*)gsrc + t * 16 + i * 4096,
                            (char*)lds_B + t * 16 + i * 4096);
        }
        __syncthreads();  // staging landed (barrier drains vmcnt)

        const int G = s * 4 + h4;  // global 8-k group
        const int aoff = ((G & ~7) | ((G ^ (cl16 & 7)) & 7)) << 3;
        const half8 a0 = *(const half8*)(lds_A + cl16 * KP + aoff);
        const half8 a1 = *(const half8*)(lds_A + (16 + cl16) * KP + aoff);
        #pragma unroll
        for (int nt = 0; nt < 10; ++nt) {
            int ntile = wv * 10 + nt;
            const half8 b = *(const half8*)(lds_B + (ntile * 16 + cl16) * 32 + ((h4 ^ bxor) << 3));
            acc[0][nt] = __builtin_amdgcn_mfma_f32_16x16x32_f16(a0, b, acc[0][nt], 0, 0, 0);
            acc[1][nt] = __builtin_amdgcn_mfma_f32_16x16x32_f16(a1, b, acc[1][nt], 0, 0, 0);
        }
    }

    __syncthreads();  // all B reads done; reuse lds_B as hid[32][HIDP]

    // ---- epilogue 1: silu -> fp16 hid (bijective swizzle for GEMM2 a-frags)
    #pragma unroll
    for (int mt = 0; mt < 2; ++mt) {
        #pragma unroll
        for (int nt = 0; nt < 10; ++nt) {
            int ntile = wv * 10 + nt;
            int hcol = ntile * 16 + cl16;        // C col = lane&15; < 640 always
            float bias = (hcol < EHID) ? b1[hcol] : 0.f;
            int gcol = hcol >> 3;                // 0..79
            #pragma unroll
            for (int r = 0; r < 4; ++r) {
                int edge = mt * 16 + h4 * 4 + r;   // C row = (lane>>4)*4 + r
                float v = (hcol < EHID) ? silu_f(acc[mt][nt][r] + bias) : 0.f;
                lds_B[edge * HIDP + (((gcol & ~7) | ((gcol ^ edge) & 7)) << 3) + (hcol & 7)]
                    = (_Float16)v;
            }
        }
    }
    __syncthreads();

    // ---- GEMM2: [32 x 640] @ [640 x 16], 16x16x32 fp16 MFMA (waves 0,1)
    if (wv < 2) {
        f32x4 acc2 = {};
        const int oc = cl16;
        const int edgeA = wv * 16 + oc;     // a-frag row
        #pragma unroll
        for (int ks = 0; ks < 20; ++ks) {
            int G2 = ks * 4 + h4;           // 0..79
            const half8 a = *(const half8*)(lds_B + edgeA * HIDP +
                               (((G2 & ~7) | ((G2 ^ edgeA) & 7)) << 3));
            const half8 b = *(const half8*)(w2t + oc * HIDP + ks * 32 + h4 * 8);
            acc2 = __builtin_amdgcn_mfma_f32_16x16x32_f16(a, b, acc2, 0, 0, 0);
        }
        float g = g1[oc], bb = bb1[oc], b2v = b2[oc];
        #pragma unroll
        for (int r = 0; r < 4; ++r) {
            int edge = wv * 16 + h4 * 4 + r;  // C row = (lane>>4)*4 + r
            float v = silu_f(acc2[r] + b2v);
            float s = v, s2 = v * v;
            #pragma unroll
            for (int m = 8; m >= 1; m >>= 1) {
                s  += __shfl_xor(s,  m, 16);
                s2 += __shfl_xor(s2, m, 16);
            }
            float mean = s * (1.f / 16.f);
            float var  = s2 * (1.f / 16.f) - mean * mean;
            float outv = (v - mean) * rsqrtf(var + LNEPS) * g + bb;
            atomicAdd(&m_i[(long long)dst_s[edge] * M + oc], outv);
        }
    }
}

// ---------------- Node kernel: unchanged fp32 path --------------------------
__global__ __launch_bounds__(256) void node_kernel(
    const float* __restrict__ x, const float* __restrict__ m_i,
    const float* __restrict__ en2g, const float* __restrict__ en2b,
    const float* __restrict__ nn1g, const float* __restrict__ nn1b,
    const float* __restrict__ w1, const float* __restrict__ b1,
    const float* __restrict__ w2, const float* __restrict__ b2,
    const float* __restrict__ nn2g, const float* __restrict__ nn2b,
    float* __restrict__ out)
{
    __shared__ float hin[NPB][NIN];
    __shared__ float hid[NPB][NHID];
    __shared__ float rsum[4], rsq[4];

    const int t = threadIdx.x;
    const long long nb = (long long)blockIdx.x * NPB;
    const int g = t >> 5, l = t & 31;
    const long long node = nb + g;

    {
        const float* xr = x + node * ROW + POSD;
        float vals[4]; float s = 0.f, s2 = 0.f;
        #pragma unroll
        for (int i = 0; i < 4; ++i) {
            float v = xr[l * 4 + i];
            vals[i] = v; s += v; s2 += v * v;
        }
        #pragma unroll
        for (int m = 16; m >= 1; m >>= 1) {
            s  += __shfl_xor(s,  m, 32);
            s2 += __shfl_xor(s2, m, 32);
        }
        float mean = s * (1.f / 128.f);
        float var  = s2 * (1.f / 128.f) - mean * mean;
        float rs   = rsqrtf(var + LNEPS);
        #pragma unroll
        for (int i = 0; i < 4; ++i) {
            int c = l * 4 + i;
            hin[g][c] = (vals[i] - mean) * rs * nn1g[c] + nn1b[c];
        }
    }
    if (l < 16) {
        float v = m_i[node * M + l];
        float a = v, a2 = v * v;
        #pragma unroll
        for (int m = 8; m >= 1; m >>= 1) {
            a  += __shfl_xor(a,  m, 16);
            a2 += __shfl_xor(a2, m, 16);
        }
        float mn = a * (1.f / 16.f);
        float vr = a2 * (1.f / 16.f) - mn * mn;
        float r2 = rsqrtf(vr + LNEPS);
        hin[g][F + l] = (v - mn) * r2 * en2g[l] + en2b[l];
    }
    __syncthreads();

    {
        float acc[NPB];
        #pragma unroll
        for (int e = 0; e < NPB; ++e) acc[e] = 0.f;
        for (int k = 0; k < NIN; ++k) {
            float w = w1[k * NHID + t];
            #pragma unroll
            for (int e = 0; e < NPB; ++e)
                acc[e] = fmaf(hin[e][k], w, acc[e]);
        }
        float b = b1[t];
        #pragma unroll
        for (int e = 0; e < NPB; ++e)
            hid[e][t] = silu_f(acc[e] + b);
    }
    __syncthreads();

    const int col = t & 127;
    const int sub = t >> 7;
    const int wvv = t >> 6;
    for (int p = 0; p < 4; ++p) {
        int e = p * 2 + sub;
        float y = b2[col];
        for (int k = 0; k < NHID; ++k)
            y = fmaf(hid[e][k], w2[k * F + col], y);
        float a = y, a2 = y * y;
        #pragma unroll
        for (int m = 32; m >= 1; m >>= 1) {
            a  += __shfl_xor(a,  m, 64);
            a2 += __shfl_xor(a2, m, 64);
        }
        if ((t & 63) == 0) { rsum[wvv] = a; rsq[wvv] = a2; }
        __syncthreads();
        float ts  = rsum[sub * 2] + rsum[sub * 2 + 1];
        float ts2 = rsq[sub * 2]  + rsq[sub * 2 + 1];
        float mn  = ts * (1.f / 128.f);
        float vr  = ts2 * (1.f / 128.f) - mn * mn;
        float r   = rsqrtf(vr + LNEPS);
        long long no = nb + e;
        float res = x[no * ROW + POSD + col];
        out[no * ROW + POSD + col] = res + (y - mn) * r * nn2g[col] + nn2b[col];
        if (col < POSD)
            out[no * ROW + col] = x[no * ROW + col];
        __syncthreads();
    }
}

extern "C" void kernel_launch(void* const* d_in, const int* in_sizes, int n_in,
                              void* d_out, int out_size, void* d_ws, size_t ws_size,
                              hipStream_t stream) {
    const float* x    = (const float*)d_in[0];
    const int*   ei   = (const int*)d_in[1];
    const float* e_w1 = (const float*)d_in[2];
    const float* e_b1 = (const float*)d_in[3];
    const float* e_w2 = (const float*)d_in[4];
    const float* e_b2 = (const float*)d_in[5];
    const float* en1g = (const float*)d_in[6];
    const float* en1b = (const float*)d_in[7];
    const float* en2g = (const float*)d_in[8];
    const float* en2b = (const float*)d_in[9];
    const float* nn1g = (const float*)d_in[10];
    const float* nn1b = (const float*)d_in[11];
    const float* n_w1 = (const float*)d_in[12];
    const float* n_b1 = (const float*)d_in[13];
    const float* n_w2 = (const float*)d_in[14];
    const float* n_b2 = (const float*)d_in[15];
    const float* nn2g = (const float*)d_in[16];
    const float* nn2b = (const float*)d_in[17];
    float* out = (float*)d_out;

    char* ws = (char*)d_ws;
    float* m_i = (float*)ws;                                  // 6,400,000 B
    _Float16* w1ks = (_Float16*)(ws + 6400000);               //   409,600 B
    _Float16* w2t  = (_Float16*)(ws + 6400000 + 409600);      //    20,480 B

    hipMemsetAsync(m_i, 0, (size_t)N_NODES * M * sizeof(float), stream);
    prep_weights<<<840, 256, 0, stream>>>(e_w1, e_w2, w1ks, w2t);
    edge_kernel<<<N_EDGES / EPB, 256, 0, stream>>>(
        x, ei, w1ks, e_b1, w2t, e_b2, en1g, en1b, m_i);
    node_kernel<<<N_NODES / NPB, 256, 0, stream>>>(
        x, m_i, en2g, en2b, nn1g, nn1b, n_w1, n_b1, n_w2, n_b2, nn2g, nn2b, out);
}

// Round 6
// 1144.006 us; speedup vs baseline: 3.3614x; 1.0310x over previous
//
#include <hip/hip_runtime.h>
#include <math.h>

#define N_NODES 100000
#define N_EDGES 400000
#define POSD 3
#define F 128
#define M 16
#define EIN 289
#define EHID 578
#define NIN 144
#define NHID 256
#define ROW 131
#define LNEPS 1e-5f

// GEMM1 (edge MLP1) padded dims
#define KP 320      // K: 289 -> 320, 10 slices of 32
#define NP 640      // N: 578 -> 640, 40 tiles of 16
#define EPB 64      // edges per block (512 threads, 8 waves)
#define NSLICE 10
#define NTW 5       // n-tiles per wave (8 waves x 5 = 40)
#define HIDP 640    // GEMM2 K padding: 80 groups of 8 -> XOR swizzle bijective per row

#define NPB 8       // nodes per block (node kernel)

typedef _Float16 half8 __attribute__((ext_vector_type(8)));
typedef float f32x4 __attribute__((ext_vector_type(4)));

__device__ __forceinline__ float silu_f(float v) { return v / (1.f + __expf(-v)); }

// ---------------- weight prep: w1 -> fp16 K-sliced PLAIN (B read from L2
// direct; swizzle was only ever for LDS banks), w2 -> fp16 T -----------------
__global__ __launch_bounds__(256) void prep_weights(
    const float* __restrict__ w1, const float* __restrict__ w2,
    _Float16* __restrict__ w1ks, _Float16* __restrict__ w2t)
{
    long long idx = (long long)blockIdx.x * 256 + threadIdx.x;
    const long long n1 = (long long)NSLICE * NP * 32;  // 204800
    if (idx < n1) {
        int s   = (int)(idx / (NP * 32));
        int rem = (int)(idx - (long long)s * (NP * 32));
        int c   = rem >> 5;
        int kk  = rem & 31;
        int k   = s * 32 + kk;
        float v = (k < EIN && c < EHID) ? w1[(long long)k * EHID + c] : 0.f;
        w1ks[idx] = (_Float16)v;   // (s, c, kk) plain
    } else {
        long long j = idx - n1;
        if (j < (long long)M * HIDP) {
            int oc = (int)(j / HIDP);
            int k  = (int)(j - (long long)oc * HIDP);
            float v = (k < EHID) ? w2[(long long)k * M + oc] : 0.f;
            w2t[j] = (_Float16)v;
        }
    }
}

// ---------------- Edge kernel: barrier-free K-loop, B direct from L2 -------
// 16x16x32 layout: A row = lane&15, k-grp = lane>>4; B col = lane&15;
// C/D col = lane&15, row = (lane>>4)*4 + reg.
__global__ __launch_bounds__(512, 2) void edge_kernel(
    const float* __restrict__ x, const int* __restrict__ ei,
    const _Float16* __restrict__ w1ks, const float* __restrict__ b1,
    const _Float16* __restrict__ w2t, const float* __restrict__ b2,
    const float* __restrict__ g1, const float* __restrict__ bb1,
    float* __restrict__ m_i)
{
    __shared__ __align__(16) _Float16 lds_A[EPB * KP];    // 40960 B, swizzled
    __shared__ __align__(16) _Float16 lds_H[EPB * HIDP];  // 81920 B
    __shared__ int   src_s[EPB], dst_s[EPB];
    __shared__ float d_s[EPB];

    const int t    = threadIdx.x;
    const int lane = t & 63;
    const int wv   = t >> 6;       // 0..7
    const int cl16 = lane & 15;
    const int h4   = lane >> 4;
    const long long ebase = (long long)blockIdx.x * EPB;

    if (t < EPB) {
        int s = ei[ebase + t];
        int d = ei[(long long)N_EDGES + ebase + t];
        src_s[t] = s; dst_s[t] = d;
        float dx = x[(long long)s*ROW+0] - x[(long long)d*ROW+0];
        float dy = x[(long long)s*ROW+1] - x[(long long)d*ROW+1];
        float dz = x[(long long)s*ROW+2] - x[(long long)d*ROW+2];
        d_s[t] = dx*dx + dy*dy + dz*dz;
    }
    __syncthreads();

    // ---- A staging (fp16, XOR-swizzled): element k of row r ->
    //      r*KP + (((k>>3) ^ (r&7))<<3) + (k&7)
    for (int i = t; i < EPB * 256; i += 512) {
        int row = i >> 8, k = i & 255;
        int node = (k < F) ? dst_s[row] : src_s[row];
        float v = x[(long long)node * ROW + POSD + (k & 127)];
        lds_A[row * KP + (((k >> 3) ^ (row & 7)) << 3) + (k & 7)] = (_Float16)v;
    }
    for (int i = t; i < EPB * 64; i += 512) {
        int row = i >> 6, j = i & 63;
        int k = 256 + j;
        float v;
        if (j < 16)       v = sinf(ldexpf(d_s[row], -j));
        else if (j < 32)  v = cosf(ldexpf(d_s[row], -(j - 16)));
        else if (j == 32) v = d_s[row];
        else              v = 0.f;
        lds_A[row * KP + (((k >> 3) ^ (row & 7)) << 3) + (k & 7)] = (_Float16)v;
    }
    __syncthreads();

    // ---- GEMM1: [64 x 320] @ [320 x 640], NO barriers; B-frags from L2.
    // B elem addr = s*20480 + (ntile*16 + cl16)*32 + h4*8  (tile = 512 elems!
    // round-5 bug was ntile*1024 here = wrong columns for every tile > 0)
    f32x4 acc[4][NTW] = {};
    #pragma unroll
    for (int s = 0; s < NSLICE; ++s) {
        half8 bf[NTW];
        #pragma unroll
        for (int nt = 0; nt < NTW; ++nt) {
            int ntile = wv * NTW + nt;
            bf[nt] = *(const half8*)(w1ks + (long long)s * (NP * 32)
                                     + ntile * 512 + cl16 * 32 + h4 * 8);
        }
        const int G = s * 4 + h4;
        const int aoff = ((G & ~7) | ((G ^ (cl16 & 7)) & 7)) << 3;
        half8 af[4];
        #pragma unroll
        for (int mt = 0; mt < 4; ++mt)
            af[mt] = *(const half8*)(lds_A + (mt * 16 + cl16) * KP + aoff);
        #pragma unroll
        for (int nt = 0; nt < NTW; ++nt) {
            #pragma unroll
            for (int mt = 0; mt < 4; ++mt)
                acc[mt][nt] = __builtin_amdgcn_mfma_f32_16x16x32_f16(
                                  af[mt], bf[nt], acc[mt][nt], 0, 0, 0);
        }
    }

    // ---- epilogue 1: silu -> fp16 hid (bijective XOR swizzle)
    #pragma unroll
    for (int nt = 0; nt < NTW; ++nt) {
        int hcol = (wv * NTW + nt) * 16 + cl16;   // < 640
        float bias = (hcol < EHID) ? b1[hcol] : 0.f;
        int gcol = hcol >> 3;                     // 0..79
        #pragma unroll
        for (int mt = 0; mt < 4; ++mt) {
            #pragma unroll
            for (int r = 0; r < 4; ++r) {
                int edge = mt * 16 + h4 * 4 + r;  // 0..63
                float v = (hcol < EHID) ? silu_f(acc[mt][nt][r] + bias) : 0.f;
                lds_H[edge * HIDP + (((gcol & ~7) | ((gcol ^ edge) & 7)) << 3) + (hcol & 7)]
                    = (_Float16)v;
            }
        }
    }
    __syncthreads();

    // ---- GEMM2: [64 x 640] @ [640 x 16], waves 0..3
    if (wv < 4) {
        f32x4 acc2 = {};
        const int oc = cl16;
        const int edgeA = wv * 16 + oc;           // a-frag row 0..63
        #pragma unroll
        for (int ks = 0; ks < 20; ++ks) {
            int G2 = ks * 4 + h4;                 // 0..79
            const half8 a = *(const half8*)(lds_H + edgeA * HIDP +
                               (((G2 & ~7) | ((G2 ^ edgeA) & 7)) << 3));
            const half8 b = *(const half8*)(w2t + oc * HIDP + ks * 32 + h4 * 8);
            acc2 = __builtin_amdgcn_mfma_f32_16x16x32_f16(a, b, acc2, 0, 0, 0);
        }
        float g = g1[oc], bb = bb1[oc], b2v = b2[oc];
        #pragma unroll
        for (int r = 0; r < 4; ++r) {
            int edge = wv * 16 + h4 * 4 + r;
            float v = silu_f(acc2[r] + b2v);
            float s = v, s2 = v * v;
            #pragma unroll
            for (int m = 8; m >= 1; m >>= 1) {
                s  += __shfl_xor(s,  m, 16);
                s2 += __shfl_xor(s2, m, 16);
            }
            float mean = s * (1.f / 16.f);
            float var  = s2 * (1.f / 16.f) - mean * mean;
            float outv = (v - mean) * rsqrtf(var + LNEPS) * g + bb;
            atomicAdd(&m_i[(long long)dst_s[edge] * M + oc], outv);
        }
    }
}

// ---------------- Node kernel: unchanged fp32 path --------------------------
__global__ __launch_bounds__(256) void node_kernel(
    const float* __restrict__ x, const float* __restrict__ m_i,
    const float* __restrict__ en2g, const float* __restrict__ en2b,
    const float* __restrict__ nn1g, const float* __restrict__ nn1b,
    const float* __restrict__ w1, const float* __restrict__ b1,
    const float* __restrict__ w2, const float* __restrict__ b2,
    const float* __restrict__ nn2g, const float* __restrict__ nn2b,
    float* __restrict__ out)
{
    __shared__ float hin[NPB][NIN];
    __shared__ float hid[NPB][NHID];
    __shared__ float rsum[4], rsq[4];

    const int t = threadIdx.x;
    const long long nb = (long long)blockIdx.x * NPB;
    const int g = t >> 5, l = t & 31;
    const long long node = nb + g;

    {
        const float* xr = x + node * ROW + POSD;
        float vals[4]; float s = 0.f, s2 = 0.f;
        #pragma unroll
        for (int i = 0; i < 4; ++i) {
            float v = xr[l * 4 + i];
            vals[i] = v; s += v; s2 += v * v;
        }
        #pragma unroll
        for (int m = 16; m >= 1; m >>= 1) {
            s  += __shfl_xor(s,  m, 32);
            s2 += __shfl_xor(s2, m, 32);
        }
        float mean = s * (1.f / 128.f);
        float var  = s2 * (1.f / 128.f) - mean * mean;
        float rs   = rsqrtf(var + LNEPS);
        #pragma unroll
        for (int i = 0; i < 4; ++i) {
            int c = l * 4 + i;
            hin[g][c] = (vals[i] - mean) * rs * nn1g[c] + nn1b[c];
        }
    }
    if (l < 16) {
        float v = m_i[node * M + l];
        float a = v, a2 = v * v;
        #pragma unroll
        for (int m = 8; m >= 1; m >>= 1) {
            a  += __shfl_xor(a,  m, 16);
            a2 += __shfl_xor(a2, m, 16);
        }
        float mn = a * (1.f / 16.f);
        float vr = a2 * (1.f / 16.f) - mn * mn;
        float r2 = rsqrtf(vr + LNEPS);
        hin[g][F + l] = (v - mn) * r2 * en2g[l] + en2b[l];
    }
    __syncthreads();

    {
        float acc[NPB];
        #pragma unroll
        for (int e = 0; e < NPB; ++e) acc[e] = 0.f;
        for (int k = 0; k < NIN; ++k) {
            float w = w1[k * NHID + t];
            #pragma unroll
            for (int e = 0; e < NPB; ++e)
                acc[e] = fmaf(hin[e][k], w, acc[e]);
        }
        float b = b1[t];
        #pragma unroll
        for (int e = 0; e < NPB; ++e)
            hid[e][t] = silu_f(acc[e] + b);
    }
    __syncthreads();

    const int col = t & 127;
    const int sub = t >> 7;
    const int wvv = t >> 6;
    for (int p = 0; p < 4; ++p) {
        int e = p * 2 + sub;
        float y = b2[col];
        for (int k = 0; k < NHID; ++k)
            y = fmaf(hid[e][k], w2[k * F + col], y);
        float a = y, a2 = y * y;
        #pragma unroll
        for (int m = 32; m >= 1; m >>= 1) {
            a  += __shfl_xor(a,  m, 64);
            a2 += __shfl_xor(a2, m, 64);
        }
        if ((t & 63) == 0) { rsum[wvv] = a; rsq[wvv] = a2; }
        __syncthreads();
        float ts  = rsum[sub * 2] + rsum[sub * 2 + 1];
        float ts2 = rsq[sub * 2]  + rsq[sub * 2 + 1];
        float mn  = ts * (1.f / 128.f);
        float vr  = ts2 * (1.f / 128.f) - mn * mn;
        float r   = rsqrtf(vr + LNEPS);
        long long no = nb + e;
        float res = x[no * ROW + POSD + col];
        out[no * ROW + POSD + col] = res + (y - mn) * r * nn2g[col] + nn2b[col];
        if (col < POSD)
            out[no * ROW + col] = x[no * ROW + col];
        __syncthreads();
    }
}

extern "C" void kernel_launch(void* const* d_in, const int* in_sizes, int n_in,
                              void* d_out, int out_size, void* d_ws, size_t ws_size,
                              hipStream_t stream) {
    const float* x    = (const float*)d_in[0];
    const int*   ei   = (const int*)d_in[1];
    const float* e_w1 = (const float*)d_in[2];
    const float* e_b1 = (const float*)d_in[3];
    const float* e_w2 = (const float*)d_in[4];
    const float* e_b2 = (const float*)d_in[5];
    const float* en1g = (const float*)d_in[6];
    const float* en1b = (const float*)d_in[7];
    const float* en2g = (const float*)d_in[8];
    const float* en2b = (const float*)d_in[9];
    const float* nn1g = (const float*)d_in[10];
    const float* nn1b = (const float*)d_in[11];
    const float* n_w1 = (const float*)d_in[12];
    const float* n_b1 = (const float*)d_in[13];
    const float* n_w2 = (const float*)d_in[14];
    const float* n_b2 = (const float*)d_in[15];
    const float* nn2g = (const float*)d_in[16];
    const float* nn2b = (const float*)d_in[17];
    float* out = (float*)d_out;

    char* ws = (char*)d_ws;
    float* m_i = (float*)ws;                                  // 6,400,000 B
    _Float16* w1ks = (_Float16*)(ws + 6400000);               //   409,600 B
    _Float16* w2t  = (_Float16*)(ws + 6400000 + 409600);      //    20,480 B

    hipMemsetAsync(m_i, 0, (size_t)N_NODES * M * sizeof(float), stream);
    prep_weights<<<840, 256, 0, stream>>>(e_w1, e_w2, w1ks, w2t);
    edge_kernel<<<N_EDGES / EPB, 512, 0, stream>>>(
        x, ei, w1ks, e_b1, w2t, e_b2, en1g, en1b, m_i);
    node_kernel<<<N_NODES / NPB, 256, 0, stream>>>(
        x, m_i, en2g, en2b, nn1g, nn1b, n_w1, n_b1, n_w2, n_b2, nn2g, nn2b, out);
}

// Round 7
// 967.434 us; speedup vs baseline: 3.9749x; 1.1825x over previous
//
#include <hip/hip_runtime.h>
#include <math.h>

#define N_NODES 100000
#define N_EDGES 400000
#define POSD 3
#define F 128
#define M 16
#define EIN 289
#define EHID 578
#define NIN 144
#define NHID 256
#define ROW 131
#define LNEPS 1e-5f

// GEMM1 (edge MLP1) padded dims
#define KP 320      // K: 289 -> 320, 10 slices of 32
#define NP 640      // N: 578 -> 640, 40 tiles of 16
#define EPB 32      // edges per block (512 threads, 8 waves)
#define NSLICE 10
#define NTW 5       // n-tiles per wave (8 waves x 5 = 40)
#define HIDP 640    // GEMM2 K padding: 80 groups of 8 -> XOR swizzle bijective per row

#define NPB 8       // nodes per block (node kernel)

typedef _Float16 half8 __attribute__((ext_vector_type(8)));
typedef float f32x4 __attribute__((ext_vector_type(4)));

__device__ __forceinline__ float silu_f(float v) { return v / (1.f + __expf(-v)); }

// ---------------- prep: x feats -> fp16 [N][128] aligned ------------------
__global__ __launch_bounds__(256) void prep_feats(
    const float* __restrict__ x, _Float16* __restrict__ feats)
{
    long long i = (long long)blockIdx.x * 256 + threadIdx.x;
    if (i < (long long)N_NODES * F) {
        int n = (int)(i >> 7), k = (int)(i & 127);
        feats[i] = (_Float16)x[(long long)n * ROW + POSD + k];
    }
}

// ---------------- prep: w1 -> fp16 K-sliced plain, w2 -> fp16 T -------------
__global__ __launch_bounds__(256) void prep_weights(
    const float* __restrict__ w1, const float* __restrict__ w2,
    _Float16* __restrict__ w1ks, _Float16* __restrict__ w2t)
{
    long long idx = (long long)blockIdx.x * 256 + threadIdx.x;
    const long long n1 = (long long)NSLICE * NP * 32;  // 204800
    if (idx < n1) {
        int s   = (int)(idx / (NP * 32));
        int rem = (int)(idx - (long long)s * (NP * 32));
        int c   = rem >> 5;
        int kk  = rem & 31;
        int k   = s * 32 + kk;
        float v = (k < EIN && c < EHID) ? w1[(long long)k * EHID + c] : 0.f;
        w1ks[idx] = (_Float16)v;   // (slice, col, kk) plain
    } else {
        long long j = idx - n1;
        if (j < (long long)M * HIDP) {
            int oc = (int)(j / HIDP);
            int k  = (int)(j - (long long)oc * HIDP);
            float v = (k < EHID) ? w2[(long long)k * M + oc] : 0.f;
            w2t[j] = (_Float16)v;
        }
    }
}

// ---------------- Edge kernel -----------------------------------------------
// 16x16x32 layout: A row = lane&15, k-grp = lane>>4; B col = lane&15;
// C/D col = lane&15, row = (lane>>4)*4 + reg.
// LDS: union — GEMM1 phase uses first EPB*KP as swizzled A; after a barrier
// the whole buffer becomes hid[32][640] (A is dead then).
__global__ __launch_bounds__(512, 4) void edge_kernel(
    const _Float16* __restrict__ feats, const float* __restrict__ x,
    const int* __restrict__ ei,
    const _Float16* __restrict__ w1ks, const float* __restrict__ b1,
    const _Float16* __restrict__ w2t, const float* __restrict__ b2,
    const float* __restrict__ g1, const float* __restrict__ bb1,
    float* __restrict__ m_i)
{
    __shared__ __align__(16) _Float16 smem[EPB * HIDP];  // 40960 B (union)
    _Float16* lds_A = smem;     // [32][320] swizzled, first 20480 B
    _Float16* lds_H = smem;     // [32][640] swizzled, full
    __shared__ int   src_s[EPB], dst_s[EPB];
    __shared__ float d_s[EPB];

    const int t    = threadIdx.x;
    const int lane = t & 63;
    const int wv   = t >> 6;       // 0..7
    const int cl16 = lane & 15;
    const int h4   = lane >> 4;
    const long long ebase = (long long)blockIdx.x * EPB;

    if (t < EPB) {
        int s = ei[ebase + t];
        int d = ei[(long long)N_EDGES + ebase + t];
        src_s[t] = s; dst_s[t] = d;
        float dx = x[(long long)s*ROW+0] - x[(long long)d*ROW+0];
        float dy = x[(long long)s*ROW+1] - x[(long long)d*ROW+1];
        float dz = x[(long long)s*ROW+2] - x[(long long)d*ROW+2];
        d_s[t] = dx*dx + dy*dy + dz*dz;
    }
    __syncthreads();

    // ---- A staging: feats part, 16B half8 loads, swizzled 16B LDS writes.
    // element k of row r -> r*KP + (((k>>3)^(r&7))<<3) + (k&7); k = 8g here.
    for (int i = t; i < EPB * 32; i += 512) {
        int row = i >> 5, g = i & 31;                 // g = k>>3, k = g*8
        int node = (g < 16) ? dst_s[row] : src_s[row];
        half8 v = *(const half8*)(feats + (long long)node * F + ((g & 15) << 3));
        *(half8*)(lds_A + row * KP + ((g ^ (row & 7)) << 3)) = v;
    }
    // ---- A staging: rbf + d + pad, k = 256..319 (scalar)
    for (int i = t; i < EPB * 64; i += 512) {
        int row = i >> 6, j = i & 63;
        float v;
        if (j < 16)       v = __sinf(ldexpf(d_s[row], -j));
        else if (j < 32)  v = __cosf(ldexpf(d_s[row], -(j - 16)));
        else if (j == 32) v = d_s[row];
        else              v = 0.f;
        int g = 32 + (j >> 3);
        lds_A[row * KP + ((g ^ (row & 7)) << 3) + (j & 7)] = (_Float16)v;
    }
    __syncthreads();

    // ---- GEMM1: [32 x 320] @ [320 x 640]; B-frags direct from L2
    f32x4 acc[2][NTW] = {};
    #pragma unroll
    for (int s = 0; s < NSLICE; ++s) {
        half8 bf[NTW];
        #pragma unroll
        for (int nt = 0; nt < NTW; ++nt) {
            int ntile = wv * NTW + nt;
            bf[nt] = *(const half8*)(w1ks + (long long)s * (NP * 32)
                                     + ntile * 512 + cl16 * 32 + h4 * 8);
        }
        const int G = s * 4 + h4;
        const int aoff = ((G & ~7) | ((G ^ (cl16 & 7)) & 7)) << 3;
        half8 af[2];
        #pragma unroll
        for (int mt = 0; mt < 2; ++mt)
            af[mt] = *(const half8*)(lds_A + (mt * 16 + cl16) * KP + aoff);
        #pragma unroll
        for (int nt = 0; nt < NTW; ++nt) {
            #pragma unroll
            for (int mt = 0; mt < 2; ++mt)
                acc[mt][nt] = __builtin_amdgcn_mfma_f32_16x16x32_f16(
                                  af[mt], bf[nt], acc[mt][nt], 0, 0, 0);
        }
    }
    __syncthreads();   // all GEMM1 LDS reads done; union region becomes hid

    // ---- epilogue 1: silu -> fp16 hid (bijective XOR swizzle over [32][640])
    #pragma unroll
    for (int nt = 0; nt < NTW; ++nt) {
        int hcol = (wv * NTW + nt) * 16 + cl16;   // < 640
        float bias = (hcol < EHID) ? b1[hcol] : 0.f;
        int gcol = hcol >> 3;                     // 0..79
        #pragma unroll
        for (int mt = 0; mt < 2; ++mt) {
            #pragma unroll
            for (int r = 0; r < 4; ++r) {
                int edge = mt * 16 + h4 * 4 + r;  // 0..31
                float v = (hcol < EHID) ? silu_f(acc[mt][nt][r] + bias) : 0.f;
                lds_H[edge * HIDP + (((gcol & ~7) | ((gcol ^ edge) & 7)) << 3) + (hcol & 7)]
                    = (_Float16)v;
            }
        }
    }
    __syncthreads();

    // ---- GEMM2: [32 x 640] @ [640 x 16], waves 0..1
    if (wv < 2) {
        f32x4 acc2 = {};
        const int oc = cl16;
        const int edgeA = wv * 16 + oc;           // a-frag row 0..31
        #pragma unroll
        for (int ks = 0; ks < 20; ++ks) {
            int G2 = ks * 4 + h4;                 // 0..79
            const half8 a = *(const half8*)(lds_H + edgeA * HIDP +
                               (((G2 & ~7) | ((G2 ^ edgeA) & 7)) << 3));
            const half8 b = *(const half8*)(w2t + oc * HIDP + ks * 32 + h4 * 8);
            acc2 = __builtin_amdgcn_mfma_f32_16x16x32_f16(a, b, acc2, 0, 0, 0);
        }
        float g = g1[oc], bb = bb1[oc], b2v = b2[oc];
        #pragma unroll
        for (int r = 0; r < 4; ++r) {
            int edge = wv * 16 + h4 * 4 + r;      // 0..31
            float v = silu_f(acc2[r] + b2v);
            float s = v, s2 = v * v;
            #pragma unroll
            for (int m = 8; m >= 1; m >>= 1) {
                s  += __shfl_xor(s,  m, 16);
                s2 += __shfl_xor(s2, m, 16);
            }
            float mean = s * (1.f / 16.f);
            float var  = s2 * (1.f / 16.f) - mean * mean;
            float outv = (v - mean) * rsqrtf(var + LNEPS) * g + bb;
            atomicAdd(&m_i[(long long)dst_s[edge] * M + oc], outv);
        }
    }
}

// ---------------- Node kernel: unchanged fp32 path --------------------------
__global__ __launch_bounds__(256) void node_kernel(
    const float* __restrict__ x, const float* __restrict__ m_i,
    const float* __restrict__ en2g, const float* __restrict__ en2b,
    const float* __restrict__ nn1g, const float* __restrict__ nn1b,
    const float* __restrict__ w1, const float* __restrict__ b1,
    const float* __restrict__ w2, const float* __restrict__ b2,
    const float* __restrict__ nn2g, const float* __restrict__ nn2b,
    float* __restrict__ out)
{
    __shared__ float hin[NPB][NIN];
    __shared__ float hid[NPB][NHID];
    __shared__ float rsum[4], rsq[4];

    const int t = threadIdx.x;
    const long long nb = (long long)blockIdx.x * NPB;
    const int g = t >> 5, l = t & 31;
    const long long node = nb + g;

    {
        const float* xr = x + node * ROW + POSD;
        float vals[4]; float s = 0.f, s2 = 0.f;
        #pragma unroll
        for (int i = 0; i < 4; ++i) {
            float v = xr[l * 4 + i];
            vals[i] = v; s += v; s2 += v * v;
        }
        #pragma unroll
        for (int m = 16; m >= 1; m >>= 1) {
            s  += __shfl_xor(s,  m, 32);
            s2 += __shfl_xor(s2, m, 32);
        }
        float mean = s * (1.f / 128.f);
        float var  = s2 * (1.f / 128.f) - mean * mean;
        float rs   = rsqrtf(var + LNEPS);
        #pragma unroll
        for (int i = 0; i < 4; ++i) {
            int c = l * 4 + i;
            hin[g][c] = (vals[i] - mean) * rs * nn1g[c] + nn1b[c];
        }
    }
    if (l < 16) {
        float v = m_i[node * M + l];
        float a = v, a2 = v * v;
        #pragma unroll
        for (int m = 8; m >= 1; m >>= 1) {
            a  += __shfl_xor(a,  m, 16);
            a2 += __shfl_xor(a2, m, 16);
        }
        float mn = a * (1.f / 16.f);
        float vr = a2 * (1.f / 16.f) - mn * mn;
        float r2 = rsqrtf(vr + LNEPS);
        hin[g][F + l] = (v - mn) * r2 * en2g[l] + en2b[l];
    }
    __syncthreads();

    {
        float acc[NPB];
        #pragma unroll
        for (int e = 0; e < NPB; ++e) acc[e] = 0.f;
        for (int k = 0; k < NIN; ++k) {
            float w = w1[k * NHID + t];
            #pragma unroll
            for (int e = 0; e < NPB; ++e)
                acc[e] = fmaf(hin[e][k], w, acc[e]);
        }
        float b = b1[t];
        #pragma unroll
        for (int e = 0; e < NPB; ++e)
            hid[e][t] = silu_f(acc[e] + b);
    }
    __syncthreads();

    const int col = t & 127;
    const int sub = t >> 7;
    const int wvv = t >> 6;
    for (int p = 0; p < 4; ++p) {
        int e = p * 2 + sub;
        float y = b2[col];
        for (int k = 0; k < NHID; ++k)
            y = fmaf(hid[e][k], w2[k * F + col], y);
        float a = y, a2 = y * y;
        #pragma unroll
        for (int m = 32; m >= 1; m >>= 1) {
            a  += __shfl_xor(a,  m, 64);
            a2 += __shfl_xor(a2, m, 64);
        }
        if ((t & 63) == 0) { rsum[wvv] = a; rsq[wvv] = a2; }
        __syncthreads();
        float ts  = rsum[sub * 2] + rsum[sub * 2 + 1];
        float ts2 = rsq[sub * 2]  + rsq[sub * 2 + 1];
        float mn  = ts * (1.f / 128.f);
        float vr  = ts2 * (1.f / 128.f) - mn * mn;
        float r   = rsqrtf(vr + LNEPS);
        long long no = nb + e;
        float res = x[no * ROW + POSD + col];
        out[no * ROW + POSD + col] = res + (y - mn) * r * nn2g[col] + nn2b[col];
        if (col < POSD)
            out[no * ROW + col] = x[no * ROW + col];
        __syncthreads();
    }
}

extern "C" void kernel_launch(void* const* d_in, const int* in_sizes, int n_in,
                              void* d_out, int out_size, void* d_ws, size_t ws_size,
                              hipStream_t stream) {
    const float* x    = (const float*)d_in[0];
    const int*   ei   = (const int*)d_in[1];
    const float* e_w1 = (const float*)d_in[2];
    const float* e_b1 = (const float*)d_in[3];
    const float* e_w2 = (const float*)d_in[4];
    const float* e_b2 = (const float*)d_in[5];
    const float* en1g = (const float*)d_in[6];
    const float* en1b = (const float*)d_in[7];
    const float* en2g = (const float*)d_in[8];
    const float* en2b = (const float*)d_in[9];
    const float* nn1g = (const float*)d_in[10];
    const float* nn1b = (const float*)d_in[11];
    const float* n_w1 = (const float*)d_in[12];
    const float* n_b1 = (const float*)d_in[13];
    const float* n_w2 = (const float*)d_in[14];
    const float* n_b2 = (const float*)d_in[15];
    const float* nn2g = (const float*)d_in[16];
    const float* nn2b = (const float*)d_in[17];
    float* out = (float*)d_out;

    char* ws = (char*)d_ws;
    float*    m_i   = (float*)ws;                         // 6,400,000 B
    _Float16* w1ks  = (_Float16*)(ws + 6400000);          //   409,600 B
    _Float16* w2t   = (_Float16*)(ws + 6809600);          //    20,480 B
    _Float16* feats = (_Float16*)(ws + 6830080);          // 25,600,000 B (tot ~32.4 MB)

    hipMemsetAsync(m_i, 0, (size_t)N_NODES * M * sizeof(float), stream);
    prep_weights<<<840, 256, 0, stream>>>(e_w1, e_w2, w1ks, w2t);
    prep_feats<<<(N_NODES * F + 255) / 256, 256, 0, stream>>>(x, feats);
    edge_kernel<<<N_EDGES / EPB, 512, 0, stream>>>(
        feats, x, ei, w1ks, e_b1, w2t, e_b2, en1g, en1b, m_i);
    node_kernel<<<N_NODES / NPB, 256, 0, stream>>>(
        x, m_i, en2g, en2b, nn1g, nn1b, n_w1, n_b1, n_w2, n_b2, nn2g, nn2b, out);
}

// Round 10
// 565.947 us; speedup vs baseline: 6.7947x; 1.7094x over previous
//
#include <hip/hip_runtime.h>
#include <math.h>

#define N_NODES 100000
#define N_EDGES 400000
#define POSD 3
#define F 128
#define M 16
#define EIN 289
#define EHID 578
#define NIN 144
#define NHID 256
#define ROW 131
#define LNEPS 1e-5f

// GEMM1 (edge MLP1) padded dims
#define KP 320      // K: 289 -> 320, 10 slices of 32 (40 groups: complete XOR sets)
#define NP 640      // N: 578 -> 640, 40 tiles of 16
#define EPB 32      // edges per block (512 threads, 8 waves)
#define NSLICE 10
#define NTW 5       // n-tiles per wave (8 waves x 5 = 40)
#define HIDP 640    // edge GEMM2 K pad: 80 groups (complete sets)

// node kernel (MFMA) — PLAIN padded LDS layout, no swizzle
#define NPB2 80     // nodes per block (1250 blocks exactly)
#define NK1 160     // node GEMM1 K: 144 -> 160 (5 slices of 32)
#define NK1P 168    // A row stride: 160 + 8 pad (336 B = 84 dwords = 20 mod 32)
#define NSL2 5
#define NHIDP 264   // H row stride: 256 + 8 pad (528 B = 132 dwords = 4 mod 32)

typedef _Float16 half8 __attribute__((ext_vector_type(8)));
typedef _Float16 half4 __attribute__((ext_vector_type(4)));
typedef float f32x4 __attribute__((ext_vector_type(4)));

__device__ __forceinline__ float silu_f(float v) { return v / (1.f + __expf(-v)); }

// ---------------- prep: x feats -> fp16 [N][128] aligned --------------------
__global__ __launch_bounds__(256) void prep_feats(
    const float* __restrict__ x, _Float16* __restrict__ feats)
{
    long long i = (long long)blockIdx.x * 256 + threadIdx.x;
    if (i < (long long)N_NODES * F) {
        int n = (int)(i >> 7), k = (int)(i & 127);
        feats[i] = (_Float16)x[(long long)n * ROW + POSD + k];
    }
}

// ---------------- prep: edge weights ----------------------------------------
__global__ __launch_bounds__(256) void prep_weights(
    const float* __restrict__ w1, const float* __restrict__ w2,
    _Float16* __restrict__ w1ks, _Float16* __restrict__ w2t)
{
    long long idx = (long long)blockIdx.x * 256 + threadIdx.x;
    const long long n1 = (long long)NSLICE * NP * 32;  // 204800
    if (idx < n1) {
        int s   = (int)(idx / (NP * 32));
        int rem = (int)(idx - (long long)s * (NP * 32));
        int c   = rem >> 5;
        int kk  = rem & 31;
        int k   = s * 32 + kk;
        float v = (k < EIN && c < EHID) ? w1[(long long)k * EHID + c] : 0.f;
        w1ks[idx] = (_Float16)v;   // (slice, col, kk) plain
    } else {
        long long j = idx - n1;
        if (j < (long long)M * HIDP) {
            int oc = (int)(j / HIDP);
            int k  = (int)(j - (long long)oc * HIDP);
            float v = (k < EHID) ? w2[(long long)k * M + oc] : 0.f;
            w2t[j] = (_Float16)v;
        }
    }
}

// ---------------- prep: node weights fp16 K-sliced --------------------------
// w1ks2: 5 slices x (256 cols x 32 kk);  w2ks: 8 slices x (128 cols x 32 kk)
__global__ __launch_bounds__(256) void prep_weights_node(
    const float* __restrict__ w1, const float* __restrict__ w2,
    _Float16* __restrict__ w1ks2, _Float16* __restrict__ w2ks)
{
    int idx = blockIdx.x * 256 + threadIdx.x;
    const int n1 = NSL2 * 256 * 32;  // 40960
    if (idx < n1) {
        int s = idx >> 13, rem = idx & 8191;
        int c = rem >> 5, kk = rem & 31;
        int k = s * 32 + kk;            // 0..159
        w1ks2[idx] = (_Float16)((k < NIN) ? w1[k * NHID + c] : 0.f);
    } else if (idx < n1 + 8 * 128 * 32) {
        int j = idx - n1;
        int s = j >> 12, rem = j & 4095;
        int c = rem >> 5, kk = rem & 31;
        int k = s * 32 + kk;            // < 256
        w2ks[j] = (_Float16)w2[k * F + c];
    }
}

// ---------------- Edge kernel (unchanged, validated) ------------------------
__global__ __launch_bounds__(512, 4) void edge_kernel(
    const _Float16* __restrict__ feats, const float* __restrict__ x,
    const int* __restrict__ ei,
    const _Float16* __restrict__ w1ks, const float* __restrict__ b1,
    const _Float16* __restrict__ w2t, const float* __restrict__ b2,
    const float* __restrict__ g1, const float* __restrict__ bb1,
    float* __restrict__ m_i)
{
    __shared__ __align__(16) _Float16 smem[EPB * HIDP];  // 40960 B (union)
    _Float16* lds_A = smem;
    _Float16* lds_H = smem;
    __shared__ int   src_s[EPB], dst_s[EPB];
    __shared__ float d_s[EPB];

    const int t    = threadIdx.x;
    const int lane = t & 63;
    const int wv   = t >> 6;
    const int cl16 = lane & 15;
    const int h4   = lane >> 4;
    const long long ebase = (long long)blockIdx.x * EPB;

    if (t < EPB) {
        int s = ei[ebase + t];
        int d = ei[(long long)N_EDGES + ebase + t];
        src_s[t] = s; dst_s[t] = d;
        float dx = x[(long long)s*ROW+0] - x[(long long)d*ROW+0];
        float dy = x[(long long)s*ROW+1] - x[(long long)d*ROW+1];
        float dz = x[(long long)s*ROW+2] - x[(long long)d*ROW+2];
        d_s[t] = dx*dx + dy*dy + dz*dz;
    }
    __syncthreads();

    for (int i = t; i < EPB * 32; i += 512) {
        int row = i >> 5, g = i & 31;
        int node = (g < 16) ? dst_s[row] : src_s[row];
        half8 v = *(const half8*)(feats + (long long)node * F + ((g & 15) << 3));
        *(half8*)(lds_A + row * KP + ((g ^ (row & 7)) << 3)) = v;
    }
    for (int i = t; i < EPB * 64; i += 512) {
        int row = i >> 6, j = i & 63;
        float v;
        if (j < 16)       v = __sinf(ldexpf(d_s[row], -j));
        else if (j < 32)  v = __cosf(ldexpf(d_s[row], -(j - 16)));
        else if (j == 32) v = d_s[row];
        else              v = 0.f;
        int g = 32 + (j >> 3);
        lds_A[row * KP + ((g ^ (row & 7)) << 3) + (j & 7)] = (_Float16)v;
    }
    __syncthreads();

    f32x4 acc[2][NTW] = {};
    #pragma unroll
    for (int s = 0; s < NSLICE; ++s) {
        half8 bf[NTW];
        #pragma unroll
        for (int nt = 0; nt < NTW; ++nt) {
            int ntile = wv * NTW + nt;
            bf[nt] = *(const half8*)(w1ks + (long long)s * (NP * 32)
                                     + ntile * 512 + cl16 * 32 + h4 * 8);
        }
        const int G = s * 4 + h4;
        const int aoff = ((G & ~7) | ((G ^ (cl16 & 7)) & 7)) << 3;
        half8 af[2];
        #pragma unroll
        for (int mt = 0; mt < 2; ++mt)
            af[mt] = *(const half8*)(lds_A + (mt * 16 + cl16) * KP + aoff);
        #pragma unroll
        for (int nt = 0; nt < NTW; ++nt) {
            #pragma unroll
            for (int mt = 0; mt < 2; ++mt)
                acc[mt][nt] = __builtin_amdgcn_mfma_f32_16x16x32_f16(
                                  af[mt], bf[nt], acc[mt][nt], 0, 0, 0);
        }
    }
    __syncthreads();

    #pragma unroll
    for (int nt = 0; nt < NTW; ++nt) {
        int hcol = (wv * NTW + nt) * 16 + cl16;
        float bias = (hcol < EHID) ? b1[hcol] : 0.f;
        int gcol = hcol >> 3;
        #pragma unroll
        for (int mt = 0; mt < 2; ++mt) {
            #pragma unroll
            for (int r = 0; r < 4; ++r) {
                int edge = mt * 16 + h4 * 4 + r;
                float v = (hcol < EHID) ? silu_f(acc[mt][nt][r] + bias) : 0.f;
                lds_H[edge * HIDP + (((gcol & ~7) | ((gcol ^ edge) & 7)) << 3) + (hcol & 7)]
                    = (_Float16)v;
            }
        }
    }
    __syncthreads();

    if (wv < 2) {
        f32x4 acc2 = {};
        const int oc = cl16;
        const int edgeA = wv * 16 + oc;
        #pragma unroll
        for (int ks = 0; ks < 20; ++ks) {
            int G2 = ks * 4 + h4;
            const half8 a = *(const half8*)(lds_H + edgeA * HIDP +
                               (((G2 & ~7) | ((G2 ^ edgeA) & 7)) << 3));
            const half8 b = *(const half8*)(w2t + oc * HIDP + ks * 32 + h4 * 8);
            acc2 = __builtin_amdgcn_mfma_f32_16x16x32_f16(a, b, acc2, 0, 0, 0);
        }
        float g = g1[oc], bb = bb1[oc], b2v = b2[oc];
        #pragma unroll
        for (int r = 0; r < 4; ++r) {
            int edge = wv * 16 + h4 * 4 + r;
            float v = silu_f(acc2[r] + b2v);
            float s = v, s2 = v * v;
            #pragma unroll
            for (int m = 8; m >= 1; m >>= 1) {
                s  += __shfl_xor(s,  m, 16);
                s2 += __shfl_xor(s2, m, 16);
            }
            float mean = s * (1.f / 16.f);
            float var  = s2 * (1.f / 16.f) - mean * mean;
            float outv = (v - mean) * rsqrtf(var + LNEPS) * g + bb;
            atomicAdd(&m_i[(long long)dst_s[edge] * M + oc], outv);
        }
    }
}

// ---------------- Node kernel: fp16 MFMA, PLAIN padded LDS (no swizzle) -----
// A = [80][NK1P=168] (160 data cols); H = [80][NHIDP=264] (256 data cols).
// Row strides 336 B / 528 B are 20 / 4 mod-32 dwords -> 2-way bank alias, free.
__global__ __launch_bounds__(512, 4) void node_kernel(
    const _Float16* __restrict__ feats, const float* __restrict__ x,
    const float* __restrict__ m_i,
    const float* __restrict__ en2g, const float* __restrict__ en2b,
    const float* __restrict__ nn1g, const float* __restrict__ nn1b,
    const _Float16* __restrict__ w1ks2, const float* __restrict__ b1,
    const _Float16* __restrict__ w2ks, const float* __restrict__ b2,
    const float* __restrict__ nn2g, const float* __restrict__ nn2b,
    float* __restrict__ out)
{
    __shared__ __align__(16) _Float16 smem[NPB2 * NHIDP];  // 42240 B (union)
    _Float16* lds_A = smem;   // [80][168], first 26880 B
    _Float16* lds_H = smem;   // [80][264]
    __shared__ float rsum2[NPB2], rsq2[NPB2];

    const int t    = threadIdx.x;
    const int lane = t & 63;
    const int wv   = t >> 6;       // 0..7
    const int cl16 = lane & 15;
    const int h4   = lane >> 4;
    const long long nb = (long long)blockIdx.x * NPB2;

    if (t < NPB2) { rsum2[t] = 0.f; rsq2[t] = 0.f; }

    // ---- LN(feats) -> lds_A cols 0..127 (plain)
    #pragma unroll
    for (int p = 0; p < 5; ++p) {
        int nl = p * 16 + (t >> 5);          // 0..79
        int l  = t & 31;
        half4 v4 = *(const half4*)(feats + (nb + nl) * F + l * 4);
        float v[4]; float s = 0.f, s2 = 0.f;
        #pragma unroll
        for (int i = 0; i < 4; ++i) {
            v[i] = (float)v4[i]; s += v[i]; s2 += v[i]*v[i];
        }
        #pragma unroll
        for (int m = 16; m >= 1; m >>= 1) {
            s  += __shfl_xor(s,  m, 32);
            s2 += __shfl_xor(s2, m, 32);
        }
        float mean = s * (1.f/128.f);
        float var  = s2 * (1.f/128.f) - mean*mean;
        float rs   = rsqrtf(var + LNEPS);
        half4 w;
        #pragma unroll
        for (int i = 0; i < 4; ++i) {
            int c = l * 4 + i;
            w[i] = (_Float16)((v[i] - mean) * rs * nn1g[c] + nn1b[c]);
        }
        *(half4*)(lds_A + nl * NK1P + l * 4) = w;
    }
    // ---- LN(m_i) -> cols 128..143 (plain)
    for (int i = t; i < NPB2 * M; i += 512) {
        int nl = i >> 4, oc = i & 15;
        float v = m_i[(nb + nl) * M + oc];
        float a = v, a2 = v * v;
        #pragma unroll
        for (int m = 8; m >= 1; m >>= 1) {
            a  += __shfl_xor(a,  m, 16);
            a2 += __shfl_xor(a2, m, 16);
        }
        float mn = a * (1.f/16.f);
        float vr = a2 * (1.f/16.f) - mn*mn;
        float lv = (v - mn) * rsqrtf(vr + LNEPS) * en2g[oc] + en2b[oc];
        lds_A[nl * NK1P + 128 + oc] = (_Float16)lv;
    }
    // ---- zeros -> cols 144..159
    for (int i = t; i < NPB2 * 16; i += 512) {
        int nl = i >> 4, j = i & 15;
        lds_A[nl * NK1P + 144 + j] = (_Float16)0.f;
    }
    __syncthreads();

    // ---- GEMM1: [80 x 160] @ [160 x 256]; wave wv owns n-tiles wv*2, wv*2+1
    f32x4 acc[5][2] = {};
    #pragma unroll
    for (int s = 0; s < NSL2; ++s) {
        half8 bf[2];
        #pragma unroll
        for (int nt = 0; nt < 2; ++nt) {
            int ntile = wv * 2 + nt;
            bf[nt] = *(const half8*)(w1ks2 + s * (NHID * 32)
                                     + ntile * 512 + cl16 * 32 + h4 * 8);
        }
        const int G = s * 4 + h4;            // 0..19
        half8 af[5];
        #pragma unroll
        for (int mt = 0; mt < 5; ++mt)
            af[mt] = *(const half8*)(lds_A + (mt * 16 + cl16) * NK1P + G * 8);
        #pragma unroll
        for (int nt = 0; nt < 2; ++nt) {
            #pragma unroll
            for (int mt = 0; mt < 5; ++mt)
                acc[mt][nt] = __builtin_amdgcn_mfma_f32_16x16x32_f16(
                                  af[mt], bf[nt], acc[mt][nt], 0, 0, 0);
        }
    }
    __syncthreads();   // A reads done; union becomes H

    // ---- epilogue 1: silu -> H [80][264] plain
    #pragma unroll
    for (int nt = 0; nt < 2; ++nt) {
        int hcol = (wv * 2 + nt) * 16 + cl16;   // 0..255
        float bias = b1[hcol];
        #pragma unroll
        for (int mt = 0; mt < 5; ++mt) {
            #pragma unroll
            for (int r = 0; r < 4; ++r) {
                int row = mt * 16 + h4 * 4 + r;  // 0..79
                float v = silu_f(acc[mt][nt][r] + bias);
                lds_H[row * NHIDP + hcol] = (_Float16)v;
            }
        }
    }
    __syncthreads();

    // ---- GEMM2: [80 x 256] @ [256 x 128]; wave wv owns out col tile wv
    f32x4 acc2[5] = {};
    const int col = wv * 16 + cl16;              // 0..127
    #pragma unroll
    for (int s = 0; s < 8; ++s) {
        const half8 b = *(const half8*)(w2ks + s * (F * 32) + col * 32 + h4 * 8);
        const int G2 = s * 4 + h4;               // 0..31
        #pragma unroll
        for (int mt = 0; mt < 5; ++mt) {
            int row = mt * 16 + cl16;
            const half8 a = *(const half8*)(lds_H + row * NHIDP + G2 * 8);
            acc2[mt] = __builtin_amdgcn_mfma_f32_16x16x32_f16(a, b, acc2[mt], 0, 0, 0);
        }
    }

    // ---- LN(128) partials: width-16 shfl + LDS atomic across waves
    float y[5][4];
    float b2v = b2[col];
    #pragma unroll
    for (int mt = 0; mt < 5; ++mt) {
        #pragma unroll
        for (int r = 0; r < 4; ++r) {
            float v = acc2[mt][r] + b2v;
            y[mt][r] = v;
            float s = v, s2 = v * v;
            #pragma unroll
            for (int m = 8; m >= 1; m >>= 1) {
                s  += __shfl_xor(s,  m, 16);
                s2 += __shfl_xor(s2, m, 16);
            }
            if (cl16 == 0) {
                int row = mt * 16 + h4 * 4 + r;
                atomicAdd(&rsum2[row], s);
                atomicAdd(&rsq2[row],  s2);
            }
        }
    }
    __syncthreads();

    // ---- finalize: LN + residual + store
    float gcol2 = nn2g[col], bcol2 = nn2b[col];
    #pragma unroll
    for (int mt = 0; mt < 5; ++mt) {
        #pragma unroll
        for (int r = 0; r < 4; ++r) {
            int row = mt * 16 + h4 * 4 + r;
            long long node = nb + row;
            float mn = rsum2[row] * (1.f/128.f);
            float vr = rsq2[row] * (1.f/128.f) - mn*mn;
            float rs = rsqrtf(vr + LNEPS);
            float res = x[node * ROW + POSD + col];
            out[node * ROW + POSD + col] = res + (y[mt][r] - mn) * rs * gcol2 + bcol2;
        }
    }
    for (int i = t; i < NPB2 * POSD; i += 512) {
        int nl = i / 3, c = i - nl * 3;
        long long node = nb + nl;
        out[node * ROW + c] = x[node * ROW + c];
    }
}

extern "C" void kernel_launch(void* const* d_in, const int* in_sizes, int n_in,
                              void* d_out, int out_size, void* d_ws, size_t ws_size,
                              hipStream_t stream) {
    const float* x    = (const float*)d_in[0];
    const int*   ei   = (const int*)d_in[1];
    const float* e_w1 = (const float*)d_in[2];
    const float* e_b1 = (const float*)d_in[3];
    const float* e_w2 = (const float*)d_in[4];
    const float* e_b2 = (const float*)d_in[5];
    const float* en1g = (const float*)d_in[6];
    const float* en1b = (const float*)d_in[7];
    const float* en2g = (const float*)d_in[8];
    const float* en2b = (const float*)d_in[9];
    const float* nn1g = (const float*)d_in[10];
    const float* nn1b = (const float*)d_in[11];
    const float* n_w1 = (const float*)d_in[12];
    const float* n_b1 = (const float*)d_in[13];
    const float* n_w2 = (const float*)d_in[14];
    const float* n_b2 = (const float*)d_in[15];
    const float* nn2g = (const float*)d_in[16];
    const float* nn2b = (const float*)d_in[17];
    float* out = (float*)d_out;

    char* ws = (char*)d_ws;
    float*    m_i   = (float*)ws;                         //  6,400,000 B
    _Float16* w1ks  = (_Float16*)(ws + 6400000);          //    409,600 B
    _Float16* w2t   = (_Float16*)(ws + 6809600);          //     20,480 B
    _Float16* feats = (_Float16*)(ws + 6830080);          // 25,600,000 B
    _Float16* w1ks2 = (_Float16*)(ws + 32430080);         //     81,920 B
    _Float16* w2ks  = (_Float16*)(ws + 32512000);         //     65,536 B

    hipMemsetAsync(m_i, 0, (size_t)N_NODES * M * sizeof(float), stream);
    prep_weights<<<840, 256, 0, stream>>>(e_w1, e_w2, w1ks, w2t);
    prep_weights_node<<<288, 256, 0, stream>>>(n_w1, n_w2, w1ks2, w2ks);
    prep_feats<<<(N_NODES * F + 255) / 256, 256, 0, stream>>>(x, feats);
    edge_kernel<<<N_EDGES / EPB, 512, 0, stream>>>(
        feats, x, ei, w1ks, e_b1, w2t, e_b2, en1g, en1b, m_i);
    node_kernel<<<N_NODES / NPB2, 512, 0, stream>>>(
        feats, x, m_i, en2g, en2b, nn1g, nn1b, w1ks2, n_b1, w2ks, n_b2, nn2g, nn2b, out);
}